// Round 23
// baseline (164.058 us; speedup 1.0000x reference)
//
#include <hip/hip_runtime.h>
#include <hip/hip_bf16.h>
#include <cmath>

typedef __attribute__((ext_vector_type(8))) short bf16x8;
typedef __attribute__((ext_vector_type(4))) short u16x4;
typedef __attribute__((ext_vector_type(4))) float f32x4;
typedef __attribute__((ext_vector_type(16))) float f32x16;
typedef unsigned short u16;
typedef unsigned int u32;

#define B_ 4
#define S_ 2048
#define H_ 512
#define NH_ 8
#define HD_ 64
#define MLP_ 2048
#define M_ (B_*S_)
#define LOG2E 1.44269504088896340736f

__device__ __forceinline__ float bf2f(u16 u){ u32 v=((u32)u)<<16; float f; __builtin_memcpy(&f,&v,4); return f; }
__device__ __forceinline__ u16 f2bf(float f){ u32 u; __builtin_memcpy(&u,&f,4); u32 r=(u+0x7fffu+((u>>16)&1u))>>16; return (u16)r; }
__device__ __forceinline__ u32 pk2(float lo, float hi2){
  __hip_bfloat162 t = __float22bfloat162_rn(make_float2(lo, hi2));
  u32 r; __builtin_memcpy(&r, &t, 4); return r;
}

__device__ __forceinline__ float xhalf_add(float x){
  float a = x, b = x;
  asm volatile("v_permlane32_swap_b32 %0, %1" : "+v"(a), "+v"(b));
  return a + b;
}

// fast gelu (tanh form) via native exp2: x * sigmoid(2.3022127x + 0.1029503x^3)
__device__ __forceinline__ float gelu_fast(float x){
  float arg = 2.30221265f*x + 0.10295034f*x*x*x;
  arg = fminf(fmaxf(arg, -30.0f), 30.0f);
  float e = __builtin_amdgcn_exp2f(arg);
  return x * e * __builtin_amdgcn_rcpf(1.0f + e);
}

__device__ __forceinline__ void gl16(const u16* g, u16* l) {
  __builtin_amdgcn_global_load_lds((const __attribute__((address_space(1))) u32*)(g),
                                   (__attribute__((address_space(3))) u32*)(l), 16, 0, 0);
}

// XCD-chunked bijective tile swizzle (all GEMM grids here have gridDim.x == 64 m-tiles,
// nwg % 8 == 0).
__device__ __forceinline__ void swz_mn(int* mt, int* nt) {
  int lin = blockIdx.x + 64*blockIdx.y;
  int xcd = lin & 7, idx = lin >> 3;
  *mt = xcd*8 + (idx & 7);
  *nt = idx >> 3;
}

// ---------------- 128x128 GEMM core, BK=64, double-buffered + counted vmcnt ------------------
__device__ __forceinline__ void gemm_core(
    const u16* __restrict__ A, const u16* __restrict__ Bt,
    int lda, int ldb, int nkt, int m0, int n0,
    u16* As, u16* Bs, f32x4 (&acc)[4][4])
{
  const int tid = threadIdx.x;
  const int lane = tid & 63;
  const int w = tid >> 6;
  const int lr = lane & 15;
  const int g  = lane >> 4;
  const int wr = w >> 1, wc = w & 1;

  const int sr = lane >> 3;
  const int scol = ((lane & 7) ^ sr) << 3;

  int aoff[2][4], boff[2][4];
#pragma unroll
  for (int m = 0; m < 4; ++m) {
    int ra = wr*64 + m*16 + lr;
    int rb = wc*64 + m*16 + lr;
#pragma unroll
    for (int kk = 0; kk < 2; ++kk) {
      aoff[kk][m] = ra*64 + (((kk*4+g) ^ (ra&7))<<3);
      boff[kk][m] = rb*64 + (((kk*4+g) ^ (rb&7))<<3);
    }
  }
  const u16* Ap = A + (size_t)m0*lda;
  const u16* Bp = Bt + (size_t)n0*ldb;

#pragma unroll
  for (int c = 0; c < 4; ++c) {
    gl16(Ap + (size_t)(w*32 + c*8 + sr)*lda + scol, As + w*2048 + c*512);
    gl16(Bp + (size_t)(w*32 + c*8 + sr)*ldb + scol, Bs + w*2048 + c*512);
  }

  for (int kt = 0; kt < nkt; ++kt) {
    const int cb = (kt & 1) * 8192;
    if (kt + 1 < nkt) {
      const int k0 = (kt + 1) << 6;
      const int nb = ((kt + 1) & 1) * 8192;
#pragma unroll
      for (int c = 0; c < 4; ++c) {
        gl16(Ap + (size_t)(w*32 + c*8 + sr)*lda + k0 + scol, As + nb + w*2048 + c*512);
        gl16(Bp + (size_t)(w*32 + c*8 + sr)*ldb + k0 + scol, Bs + nb + w*2048 + c*512);
      }
      asm volatile("s_waitcnt vmcnt(8)" ::: "memory");
    } else {
      asm volatile("s_waitcnt vmcnt(0)" ::: "memory");
    }
    __builtin_amdgcn_s_barrier();

#pragma unroll
    for (int kk = 0; kk < 2; ++kk) {
      bf16x8 af[4], bfr[4];
#pragma unroll
      for (int m = 0; m < 4; ++m) {
        af[m]  = *(const bf16x8*)(As + cb + aoff[kk][m]);
        bfr[m] = *(const bf16x8*)(Bs + cb + boff[kk][m]);
      }
#pragma unroll
      for (int m = 0; m < 4; ++m) {
#pragma unroll
        for (int n = 0; n < 4; ++n) {
          acc[m][n] = __builtin_amdgcn_mfma_f32_16x16x32_bf16(af[m], bfr[n], acc[m][n], 0, 0, 0);
        }
      }
    }
    __builtin_amdgcn_s_barrier();
  }
}

// ---------------- 128x64 GEMM core, BK=64 ----------------------------------------------------
__device__ __forceinline__ void gemm_core64(
    const u16* __restrict__ A, const u16* __restrict__ Bt,
    int lda, int ldb, int nkt, int m0, int n0,
    u16* As, u16* Bs, f32x4 (&acc)[2][4])
{
  const int tid = threadIdx.x;
  const int lane = tid & 63;
  const int w = tid >> 6;
  const int lr = lane & 15;
  const int g  = lane >> 4;

  const int sr = lane >> 3;
  const int scol = ((lane & 7) ^ sr) << 3;

  int aoff[2][2], boff[2][4];
#pragma unroll
  for (int m = 0; m < 2; ++m) {
    int ra = w*32 + m*16 + lr;
#pragma unroll
    for (int kk = 0; kk < 2; ++kk) aoff[kk][m] = ra*64 + (((kk*4+g) ^ (ra&7))<<3);
  }
#pragma unroll
  for (int n = 0; n < 4; ++n) {
    int rb = n*16 + lr;
#pragma unroll
    for (int kk = 0; kk < 2; ++kk) boff[kk][n] = rb*64 + (((kk*4+g) ^ (rb&7))<<3);
  }
  const u16* Ap = A + (size_t)m0*lda;
  const u16* Bp = Bt + (size_t)n0*ldb;

#pragma unroll
  for (int c = 0; c < 4; ++c)
    gl16(Ap + (size_t)(w*32 + c*8 + sr)*lda + scol, As + w*2048 + c*512);
#pragma unroll
  for (int c = 0; c < 2; ++c)
    gl16(Bp + (size_t)(w*16 + c*8 + sr)*ldb + scol, Bs + w*1024 + c*512);

  for (int kt = 0; kt < nkt; ++kt) {
    const int cbA = (kt & 1) * 8192;
    const int cbB = (kt & 1) * 4096;
    if (kt + 1 < nkt) {
      const int k0 = (kt + 1) << 6;
      const int nbA = ((kt + 1) & 1) * 8192;
      const int nbB = ((kt + 1) & 1) * 4096;
#pragma unroll
      for (int c = 0; c < 4; ++c)
        gl16(Ap + (size_t)(w*32 + c*8 + sr)*lda + k0 + scol, As + nbA + w*2048 + c*512);
#pragma unroll
      for (int c = 0; c < 2; ++c)
        gl16(Bp + (size_t)(w*16 + c*8 + sr)*ldb + k0 + scol, Bs + nbB + w*1024 + c*512);
      asm volatile("s_waitcnt vmcnt(6)" ::: "memory");
    } else {
      asm volatile("s_waitcnt vmcnt(0)" ::: "memory");
    }
    __builtin_amdgcn_s_barrier();

#pragma unroll
    for (int kk = 0; kk < 2; ++kk) {
      bf16x8 af[2], bfr[4];
#pragma unroll
      for (int m = 0; m < 2; ++m) af[m] = *(const bf16x8*)(As + cbA + aoff[kk][m]);
#pragma unroll
      for (int n = 0; n < 4; ++n) bfr[n] = *(const bf16x8*)(Bs + cbB + boff[kk][n]);
#pragma unroll
      for (int m = 0; m < 2; ++m) {
#pragma unroll
        for (int n = 0; n < 4; ++n) {
          acc[m][n] = __builtin_amdgcn_mfma_f32_16x16x32_bf16(af[m], bfr[n], acc[m][n], 0, 0, 0);
        }
      }
    }
    __builtin_amdgcn_s_barrier();
  }
}

// ---------------- QKV fused GEMM, 128x64 tiles (3 blocks/CU, tail-free grid) -----------------
// grid (64, 24): nt in [0,24), sel = nt>>3 (0=q,1=k,2=v), n0 = (nt&7)*64.
// q-scale folded into wqt; v written transposed into vt[bh][d][s].
__global__ __launch_bounds__(256,3) void k_qkv64(
    const u16* __restrict__ xn, const u16* __restrict__ wqt,
    const u16* __restrict__ wkt, const u16* __restrict__ wvt,
    u16* __restrict__ q, u16* __restrict__ k, u16* __restrict__ vt)
{
  __shared__ u16 As[2*128*64], Bs[2*64*64];
  int mt, nt; swz_mn(&mt, &nt);
  int m0 = mt*128;
  int sel = nt >> 3;
  int n0 = (nt & 7)*64;
  const u16* Bt = sel==0 ? wqt : (sel==1 ? wkt : wvt);
  f32x4 acc[2][4] = {};
  gemm_core64(xn, Bt, H_, H_, H_/64, m0, n0, As, Bs, acc);
  const int lane = threadIdx.x&63, w = threadIdx.x>>6;
  const int lr = lane&15, g = lane>>4;
  if (sel == 2) {
#pragma unroll
    for (int m=0;m<2;++m) {
#pragma unroll
      for (int n=0;n<4;++n) {
        int rowb = m0 + w*32 + m*16 + g*4;
        int col  = n0 + n*16 + lr;
        int b = rowb >> 11, s = rowb & 2047;
        int h = col >> 6, d = col & 63;
        u16x4 t;
#pragma unroll
        for (int r=0;r<4;++r) t[r] = (short)f2bf(acc[m][n][r]);
        *(u16x4*)(vt + ((size_t)((b*NH_ + h)*HD_ + d))*S_ + s) = t;
      }
    }
  } else {
    u16* O = sel==0 ? q : k;
#pragma unroll
    for (int m=0;m<2;++m) {
#pragma unroll
      for (int n=0;n<4;++n) {
#pragma unroll
        for (int r=0;r<4;++r) {
          int row = m0 + w*32 + m*16 + g*4 + r;
          int col = n0 + n*16 + lr;
          O[(size_t)row*H_ + col] = f2bf(acc[m][n][r]);
        }
      }
    }
  }
}

// ---------------- GEMM with epilogue, 128x128 ------------------------------------------------
// EPI 1: O(bf16) = gelu_fast(acc)
template<int EPI>
__global__ __launch_bounds__(256,2) void k_gemm(
    const u16* __restrict__ A, const u16* __restrict__ Bt, void* __restrict__ Ov,
    const void* __restrict__ aux, const float* __restrict__ maskv,
    int N, int K)
{
  __shared__ u16 As[2*128*64], Bs[2*128*64];
  int mt, nt; swz_mn(&mt, &nt);
  int m0 = mt*128, n0 = nt*128;
  f32x4 acc[4][4] = {};
  gemm_core(A, Bt, K, K, K>>6, m0, n0, As, Bs, acc);
  const int lane = threadIdx.x&63, w = threadIdx.x>>6;
  const int lr = lane&15, g = lane>>4, wr = w>>1, wc = w&1;
#pragma unroll
  for (int m=0;m<4;++m) {
#pragma unroll
    for (int n=0;n<4;++n) {
#pragma unroll
      for (int r=0;r<4;++r) {
        int row = m0 + wr*64 + m*16 + g*4 + r;
        int col = n0 + wc*64 + n*16 + lr;
        float val = acc[m][n][r];
        if (EPI == 1) {
          ((u16*)Ov)[(size_t)row*N + col] = f2bf(gelu_fast(val));
        }
      }
    }
  }
}

// ---------------- GEMM with epilogue, 128x64 -------------------------------------------------
// EPI 2: O(bf16) = (aux_f32 + acc)*maskv[row]   (Wo GEMM -> x2 in bf16)
// EPI 3: O(f32)  = acc + aux_bf16                (final: ffn + x2)
template<int EPI>
__global__ __launch_bounds__(256,3) void k_gemm64(
    const u16* __restrict__ A, const u16* __restrict__ Bt, void* __restrict__ Ov,
    const void* __restrict__ aux, const float* __restrict__ maskv,
    int N, int K)
{
  __shared__ u16 As[2*128*64], Bs[2*64*64];
  int mt, nt; swz_mn(&mt, &nt);
  int m0 = mt*128, n0 = nt*64;
  f32x4 acc[2][4] = {};
  gemm_core64(A, Bt, K, K, K>>6, m0, n0, As, Bs, acc);
  const int lane = threadIdx.x&63, w = threadIdx.x>>6;
  const int lr = lane&15, g = lane>>4;
#pragma unroll
  for (int m=0;m<2;++m) {
#pragma unroll
    for (int n=0;n<4;++n) {
#pragma unroll
      for (int r=0;r<4;++r) {
        int row = m0 + w*32 + m*16 + g*4 + r;
        int col = n0 + n*16 + lr;
        float val = acc[m][n][r];
        if (EPI == 2) {
          float mv = maskv[row];
          val = (((const float*)aux)[(size_t)row*N + col] + val)*mv;
          ((u16*)Ov)[(size_t)row*N + col] = f2bf(val);
        } else if (EPI == 3) {
          val += bf2f(((const u16*)aux)[(size_t)row*N + col]);
          ((float*)Ov)[(size_t)row*N + col] = val;
        }
      }
    }
  }
}

// ---------------- LayerNorm, bf16 input (post-attention) -------------------------------------
__global__ __launch_bounds__(256) void k_lnb(const u16* __restrict__ in,
    u16* __restrict__ out)
{
  int row = blockIdx.x*4 + (threadIdx.x>>6);
  int lane = threadIdx.x & 63;
  bf16x8 d = *(const bf16x8*)(in + (size_t)row*H_ + lane*8);
  float x[8]; float s = 0.f, s2 = 0.f;
#pragma unroll
  for (int j=0;j<8;++j){ x[j] = bf2f((u16)d[j]); s += x[j]; s2 += x[j]*x[j]; }
#pragma unroll
  for (int m=1;m<32;m<<=1){ s += __shfl_xor(s,m); s2 += __shfl_xor(s2,m); }
  s = xhalf_add(s); s2 = xhalf_add(s2);
  float mu = s*(1.0f/H_);
  float var = s2*(1.0f/H_) - mu*mu;
  float inv = rsqrtf(var + 1e-6f);
  bf16x8 o;
#pragma unroll
  for (int j=0;j<8;++j) o[j] = (short)f2bf((x[j]-mu)*inv);
  *(bf16x8*)(out + (size_t)row*H_ + lane*8) = o;
}

// ---------------- fused preprocessing: 6 weight transposes + masked LN -----------------------
// Wq is scaled by 0.125*log2e during transpose (q-scale fold).
__global__ __launch_bounds__(256) void k_pre(
    const float* __restrict__ Wq, const float* __restrict__ Wk,
    const float* __restrict__ Wv, const float* __restrict__ Wo,
    const float* __restrict__ W1, const float* __restrict__ W2,
    u16* __restrict__ wqt, u16* __restrict__ wkt, u16* __restrict__ wvt,
    u16* __restrict__ wot, u16* __restrict__ w1t, u16* __restrict__ w2t,
    const float* __restrict__ input, const float* __restrict__ mask,
    u16* __restrict__ xn)
{
  __shared__ u16 t[32][33];
  const int id = blockIdx.x;
  const int tx = threadIdx.x & 31, ty = threadIdx.x >> 5;

  if (id < 1024) {
    int z = id >> 8, tt = id & 255;
    const float* src = z==0?Wq : z==1?Wk : z==2?Wv : Wo;
    u16* dst = z==0?wqt : z==1?wkt : z==2?wvt : wot;
    float sc = (z==0) ? 0.125f*LOG2E : 1.0f;
    int c0 = (tt & 15)*32, r0 = (tt >> 4)*32;
#pragma unroll
    for (int i=0;i<32;i+=8) t[ty+i][tx] = f2bf(src[(size_t)(r0+ty+i)*512 + c0+tx]*sc);
    __syncthreads();
#pragma unroll
    for (int i=0;i<32;i+=8) dst[(size_t)(c0+ty+i)*512 + r0+tx] = t[tx][ty+i];
  } else if (id < 3072) {
    int z = (id-1024) >> 10, tt = (id-1024) & 1023;
    const float* src = z ? W2 : W1;
    u16* dst = z ? w2t : w1t;
    int R = z ? 2048 : 512;
    int C = z ? 512 : 2048;
    int a = tt & 63, bq = tt >> 6;
    int c0 = (z ? bq : a)*32;
    int r0 = (z ? a : bq)*32;
#pragma unroll
    for (int i=0;i<32;i+=8) t[ty+i][tx] = f2bf(src[(size_t)(r0+ty+i)*C + c0+tx]);
    __syncthreads();
#pragma unroll
    for (int i=0;i<32;i+=8) dst[(size_t)(c0+ty+i)*R + r0+tx] = t[tx][ty+i];
  } else {
    int row = (id-3072)*4 + (threadIdx.x>>6);
    int lane = threadIdx.x & 63;
    const f32x4* p = (const f32x4*)(input + (size_t)row*H_ + lane*8);
    f32x4 a = p[0], b = p[1];
    float mv = mask[row];
    float x[8]; float s = 0.f, s2 = 0.f;
#pragma unroll
    for (int j=0;j<4;++j){ x[j] = a[j]*mv; x[4+j] = b[j]*mv; }
#pragma unroll
    for (int j=0;j<8;++j){ s += x[j]; s2 += x[j]*x[j]; }
#pragma unroll
    for (int m=1;m<32;m<<=1){ s += __shfl_xor(s,m); s2 += __shfl_xor(s2,m); }
    s = xhalf_add(s); s2 = xhalf_add(s2);
    float mu = s*(1.0f/H_);
    float var = s2*(1.0f/H_) - mu*mu;
    float inv = rsqrtf(var + 1e-6f);
    bf16x8 o;
#pragma unroll
    for (int j=0;j<8;++j) o[j] = (short)f2bf((x[j]-mu)*inv);
    *(bf16x8*)(xn + (size_t)row*H_ + lane*8) = o;
  }
}

// ---------------- flash attention, swapped-QK^T 32x32, log2-domain softmax -------------------
__global__ __launch_bounds__(256) void k_attn(
    const u16* __restrict__ q, const u16* __restrict__ kmat,
    const u16* __restrict__ vt, const float* __restrict__ mask,
    u16* __restrict__ o)
{
  __shared__ u16 Ks[2][64*64];
  __shared__ u16 Vs[2][64*64];
  __shared__ float bias[S_];
  __shared__ float lsums[4][32];

  const int tid = threadIdx.x;
  const int lane = tid & 63;
  const int w = tid >> 6;          // 0..3
  const int l31 = lane & 31;
  const int hi = lane >> 5;
  const int bh = blockIdx.y, b = bh >> 3, h = bh & 7;
  const int q0 = blockIdx.x * 128;

  const int sr = lane >> 3;
  const int sl = (lane & 7) ^ (sr & 7);
  const u16* ks0 = kmat + (size_t)(b*S_ + w*16 + sr)*H_ + h*HD_ + sl*8;
  const u16* ks1 = ks0 + (size_t)8*H_;
  const u16* vs0 = vt + ((size_t)bh*HD_ + w*16 + sr)*S_ + sl*8;
  const u16* vs1 = vs0 + (size_t)8*S_;

  {
    u16* kd = &Ks[0][0] + w*1024;
    u16* vd = &Vs[0][0] + w*1024;
    gl16(ks0, kd); gl16(ks1, kd + 512);
    gl16(vs0, vd); gl16(vs1, vd + 512);
  }

  // bias in log2 units
  for (int j = tid; j < S_; j += 256) bias[j] = -144269.5f * (1.0f - mask[b*S_ + j]);

  bf16x8 qf[4];
  {
    const u16* qp = q + (size_t)(b*S_ + q0 + w*32 + l31)*H_ + h*HD_ + hi*8;
#pragma unroll
    for (int ds = 0; ds < 4; ++ds) qf[ds] = *(const bf16x8*)(qp + ds*16);
  }

  f32x16 po0 = {}, po1 = {};
  float mreg = -1e30f, lsum = 0.f;

  __syncthreads();   // bias + tile0 visible (full drain once)

  for (int jt = 0; jt < 32; ++jt) {
    const int buf = jt & 1;
    if (jt < 31) {
      const int j0 = (jt + 1) * 64;
      u16* kd = &Ks[buf ^ 1][0] + w*1024;
      u16* vd = &Vs[buf ^ 1][0] + w*1024;
      gl16(ks0 + (size_t)j0*H_, kd); gl16(ks1 + (size_t)j0*H_, kd + 512);
      gl16(vs0 + j0, vd);            gl16(vs1 + j0, vd + 512);
      asm volatile("s_waitcnt vmcnt(4)" ::: "memory");
    } else {
      asm volatile("s_waitcnt vmcnt(0)" ::: "memory");
    }
    __builtin_amdgcn_s_barrier();

    const u16* kt  = &Ks[buf][0];
    const u16* vtl = &Vs[buf][0];

    // ---- QK^T (S^T, log2 units), bias as MFMA C-input ----
    f32x16 s0, s1;
    const float* bp = &bias[jt*64 + hi*4];
#pragma unroll
    for (int kb = 0; kb < 2; ++kb) {
      f32x16 acc;
#pragma unroll
      for (int g2 = 0; g2 < 4; ++g2) {
        f32x4 b4 = *(const f32x4*)(bp + kb*32 + g2*8);
        acc[g2*4+0] = b4[0]; acc[g2*4+1] = b4[1];
        acc[g2*4+2] = b4[2]; acc[g2*4+3] = b4[3];
      }
      const int key = kb*32 + l31;
      const u16* kr = kt + key*64;
      __builtin_amdgcn_s_setprio(1);
#pragma unroll
      for (int ds = 0; ds < 4; ++ds) {
        bf16x8 kf = *(const bf16x8*)(kr + (((ds*2 + hi) ^ (key & 7)) << 3));
        acc = __builtin_amdgcn_mfma_f32_32x32x16_bf16(kf, qf[ds], acc, 0, 0, 0);
      }
      __builtin_amdgcn_s_setprio(0);
      if (kb == 0) s0 = acc; else s1 = acc;
    }

    // ---- online softmax; max via v_max3 fusion, exp2 single-instr ----
    float mx = fmaxf(s0[0], s1[0]);
#pragma unroll
    for (int r = 1; r < 16; ++r) mx = fmaxf(fmaxf(s0[r], s1[r]), mx);
    mx = fmaxf(mx, __shfl_xor(mx, 32));
    if (__any(mx > mreg + 8.0f)) {          // defer-max (log2 units; P <= 2^8)
      float mn = fmaxf(mreg, mx);
      float sc = __builtin_amdgcn_exp2f(mreg - mn);
      lsum *= sc;
#pragma unroll
      for (int r = 0; r < 16; ++r) { po0[r] *= sc; po1[r] *= sc; }
      mreg = mn;
    }
    float ps = 0.f;
#pragma unroll
    for (int r = 0; r < 16; ++r) { float p = __builtin_amdgcn_exp2f(s0[r]-mreg); s0[r] = p; ps += p; }
#pragma unroll
    for (int r = 0; r < 16; ++r) { float p = __builtin_amdgcn_exp2f(s1[r]-mreg); s1[r] = p; ps += p; }
    ps += __shfl_xor(ps, 32);
    lsum += ps;

    // ---- P -> A-frags (cvt_pk + permlane32_swap) + PV ----
#pragma unroll
    for (int kb = 0; kb < 2; ++kb) {
      const f32x16& sv = kb ? s1 : s0;
      u32 w01 = pk2(sv[0],  sv[1]);
      u32 w23 = pk2(sv[2],  sv[3]);
      u32 w45 = pk2(sv[4],  sv[5]);
      u32 w67 = pk2(sv[6],  sv[7]);
      asm volatile("v_permlane32_swap_b32 %0, %1" : "+v"(w01), "+v"(w45));
      asm volatile("v_permlane32_swap_b32 %0, %1" : "+v"(w23), "+v"(w67));
      u32 w89 = pk2(sv[8],  sv[9]);
      u32 wab = pk2(sv[10], sv[11]);
      u32 wcd = pk2(sv[12], sv[13]);
      u32 wef = pk2(sv[14], sv[15]);
      asm volatile("v_permlane32_swap_b32 %0, %1" : "+v"(w89), "+v"(wcd));
      asm volatile("v_permlane32_swap_b32 %0, %1" : "+v"(wab), "+v"(wef));
      union { u32 wrd[4]; bf16x8 v; } f0, f1;
      f0.wrd[0]=w01; f0.wrd[1]=w23; f0.wrd[2]=w45; f0.wrd[3]=w67;
      f1.wrd[0]=w89; f1.wrd[1]=wab; f1.wrd[2]=wcd; f1.wrd[3]=wef;
      __builtin_amdgcn_s_setprio(1);
#pragma unroll
      for (int ks = 0; ks < 2; ++ks) {
        bf16x8 pa = ks ? f1.v : f0.v;
#pragma unroll
        for (int nb = 0; nb < 2; ++nb) {
          int dd = nb*32 + l31;
          int slot = ((kb*4 + ks*2 + hi) ^ (dd & 7)) << 3;
          bf16x8 vf = *(const bf16x8*)(vtl + dd*64 + slot);
          if (nb == 0) po0 = __builtin_amdgcn_mfma_f32_32x32x16_bf16(pa, vf, po0, 0,0,0);
          else         po1 = __builtin_amdgcn_mfma_f32_32x32x16_bf16(pa, vf, po1, 0,0,0);
        }
      }
      __builtin_amdgcn_s_setprio(0);
    }
    __builtin_amdgcn_s_barrier();
  }

  // ---- epilogue ----
  if (hi == 0) lsums[w][l31] = lsum;
  f32x4 li[4];
#pragma unroll
  for (int g2i = 0; g2i < 4; ++g2i) {
    f32x4 t = *(const f32x4*)&lsums[w][g2i*8 + hi*4];
    li[g2i][0] = 1.0f/t[0]; li[g2i][1] = 1.0f/t[1];
    li[g2i][2] = 1.0f/t[2]; li[g2i][3] = 1.0f/t[3];
  }
  u16* op = o + (size_t)(b*S_ + q0 + w*32)*H_ + h*HD_;
#pragma unroll
  for (int nb = 0; nb < 2; ++nb) {
#pragma unroll
    for (int r = 0; r < 16; ++r) {
      int row = (r&3) + 8*(r>>2) + 4*hi;
      float val = (nb ? po1[r] : po0[r]) * li[r>>2][r&3];
      op[(size_t)row*H_ + nb*32 + l31] = f2bf(val);
    }
  }
}

// ---------------- launch ---------------------------------------------------------------------
extern "C" void kernel_launch(void* const* d_in, const int* in_sizes, int n_in,
                              void* d_out, int out_size, void* d_ws, size_t ws_size,
                              hipStream_t stream) {
  const float* input = (const float*)d_in[0];
  const float* mask  = (const float*)d_in[1];
  const float* Wq = (const float*)d_in[2];
  const float* Wk = (const float*)d_in[3];
  const float* Wv = (const float*)d_in[4];
  const float* Wo = (const float*)d_in[5];
  const float* W1 = (const float*)d_in[6];
  const float* W2 = (const float*)d_in[7];
  float* out = (float*)d_out;
  u16* ws = (u16*)d_ws;

  u16* wqt = ws;                 // 512x512 bf16 (pre-scaled by 0.125*log2e)
  u16* wkt = wqt + 262144;
  u16* wvt = wkt + 262144;
  u16* wot = wvt + 262144;
  u16* w1t = wot + 262144;       // 2048x512 bf16
  u16* w2t = w1t + 1048576;      // 512x2048 bf16
  u16* xn  = w2t + 1048576;      // 8192x512 bf16
  u16* q   = xn  + 4194304;
  u16* k   = q   + 4194304;
  u16* v   = k   + 4194304;      // free region
  u16* vt  = v   + 4194304;      // 32x64x2048 bf16 (written directly by k_qkv64)
  u16*   attn = xn;              // xn dead after QKV
  u16*   x2b  = q;               // q dead after attention -> 8192x512 bf16
  u16*   y    = v;               // free region
  u16*   h1   = vt;              // vt dead after attention (8192x2048 bf16)

  dim3 blk(256);
  k_pre<<<dim3(5120), blk, 0, stream>>>(Wq, Wk, Wv, Wo, W1, W2,
                                        wqt, wkt, wvt, wot, w1t, w2t,
                                        input, mask, xn);
  k_qkv64<<<dim3(64,24), blk, 0, stream>>>(xn, wqt, wkt, wvt, q, k, vt);
  k_attn<<<dim3(16,32), blk, 0, stream>>>(q, k, vt, mask, attn);
  k_gemm64<2><<<dim3(64,8), blk, 0, stream>>>(attn, wot, (void*)x2b, (const void*)input, mask, 512, 512);
  k_lnb<<<2048, blk, 0, stream>>>(x2b, y);
  k_gemm<1><<<dim3(64,16), blk, 0, stream>>>(y, w1t, (void*)h1, nullptr, nullptr, 2048, 512);
  k_gemm64<3><<<dim3(64,8), blk, 0, stream>>>(h1, w2t, (void*)out, (const void*)x2b, nullptr, 512, 2048);
}

// Round 24
// 163.336 us; speedup vs baseline: 1.0044x; 1.0044x over previous
//
#include <hip/hip_runtime.h>
#include <hip/hip_bf16.h>
#include <cmath>

typedef __attribute__((ext_vector_type(8))) short bf16x8;
typedef __attribute__((ext_vector_type(4))) short u16x4;
typedef __attribute__((ext_vector_type(4))) float f32x4;
typedef __attribute__((ext_vector_type(16))) float f32x16;
typedef unsigned short u16;
typedef unsigned int u32;

#define B_ 4
#define S_ 2048
#define H_ 512
#define NH_ 8
#define HD_ 64
#define MLP_ 2048
#define M_ (B_*S_)
#define LOG2E 1.44269504088896340736f

__device__ __forceinline__ float bf2f(u16 u){ u32 v=((u32)u)<<16; float f; __builtin_memcpy(&f,&v,4); return f; }
__device__ __forceinline__ u16 f2bf(float f){ u32 u; __builtin_memcpy(&u,&f,4); u32 r=(u+0x7fffu+((u>>16)&1u))>>16; return (u16)r; }
__device__ __forceinline__ u32 pk2(float lo, float hi2){
  __hip_bfloat162 t = __float22bfloat162_rn(make_float2(lo, hi2));
  u32 r; __builtin_memcpy(&r, &t, 4); return r;
}

__device__ __forceinline__ float xhalf_add(float x){
  float a = x, b = x;
  asm volatile("v_permlane32_swap_b32 %0, %1" : "+v"(a), "+v"(b));
  return a + b;
}

// fast gelu (tanh form) via native exp2: x * sigmoid(2.3022127x + 0.1029503x^3)
__device__ __forceinline__ float gelu_fast(float x){
  float arg = 2.30221265f*x + 0.10295034f*x*x*x;
  arg = fminf(fmaxf(arg, -30.0f), 30.0f);
  float e = __builtin_amdgcn_exp2f(arg);
  return x * e * __builtin_amdgcn_rcpf(1.0f + e);
}

__device__ __forceinline__ void gl16(const u16* g, u16* l) {
  __builtin_amdgcn_global_load_lds((const __attribute__((address_space(1))) u32*)(g),
                                   (__attribute__((address_space(3))) u32*)(l), 16, 0, 0);
}

// XCD-chunked bijective tile swizzle (all GEMM grids here have gridDim.x == 64 m-tiles,
// nwg % 8 == 0).
__device__ __forceinline__ void swz_mn(int* mt, int* nt) {
  int lin = blockIdx.x + 64*blockIdx.y;
  int xcd = lin & 7, idx = lin >> 3;
  *mt = xcd*8 + (idx & 7);
  *nt = idx >> 3;
}

// ---------------- 128x128 GEMM core, BK=64, double-buffered + counted vmcnt ------------------
__device__ __forceinline__ void gemm_core(
    const u16* __restrict__ A, const u16* __restrict__ Bt,
    int lda, int ldb, int nkt, int m0, int n0,
    u16* As, u16* Bs, f32x4 (&acc)[4][4])
{
  const int tid = threadIdx.x;
  const int lane = tid & 63;
  const int w = tid >> 6;
  const int lr = lane & 15;
  const int g  = lane >> 4;
  const int wr = w >> 1, wc = w & 1;

  const int sr = lane >> 3;
  const int scol = ((lane & 7) ^ sr) << 3;

  int aoff[2][4], boff[2][4];
#pragma unroll
  for (int m = 0; m < 4; ++m) {
    int ra = wr*64 + m*16 + lr;
    int rb = wc*64 + m*16 + lr;
#pragma unroll
    for (int kk = 0; kk < 2; ++kk) {
      aoff[kk][m] = ra*64 + (((kk*4+g) ^ (ra&7))<<3);
      boff[kk][m] = rb*64 + (((kk*4+g) ^ (rb&7))<<3);
    }
  }
  const u16* Ap = A + (size_t)m0*lda;
  const u16* Bp = Bt + (size_t)n0*ldb;

#pragma unroll
  for (int c = 0; c < 4; ++c) {
    gl16(Ap + (size_t)(w*32 + c*8 + sr)*lda + scol, As + w*2048 + c*512);
    gl16(Bp + (size_t)(w*32 + c*8 + sr)*ldb + scol, Bs + w*2048 + c*512);
  }

  for (int kt = 0; kt < nkt; ++kt) {
    const int cb = (kt & 1) * 8192;
    if (kt + 1 < nkt) {
      const int k0 = (kt + 1) << 6;
      const int nb = ((kt + 1) & 1) * 8192;
#pragma unroll
      for (int c = 0; c < 4; ++c) {
        gl16(Ap + (size_t)(w*32 + c*8 + sr)*lda + k0 + scol, As + nb + w*2048 + c*512);
        gl16(Bp + (size_t)(w*32 + c*8 + sr)*ldb + k0 + scol, Bs + nb + w*2048 + c*512);
      }
      asm volatile("s_waitcnt vmcnt(8)" ::: "memory");
    } else {
      asm volatile("s_waitcnt vmcnt(0)" ::: "memory");
    }
    __builtin_amdgcn_s_barrier();

#pragma unroll
    for (int kk = 0; kk < 2; ++kk) {
      bf16x8 af[4], bfr[4];
#pragma unroll
      for (int m = 0; m < 4; ++m) {
        af[m]  = *(const bf16x8*)(As + cb + aoff[kk][m]);
        bfr[m] = *(const bf16x8*)(Bs + cb + boff[kk][m]);
      }
#pragma unroll
      for (int m = 0; m < 4; ++m) {
#pragma unroll
        for (int n = 0; n < 4; ++n) {
          acc[m][n] = __builtin_amdgcn_mfma_f32_16x16x32_bf16(af[m], bfr[n], acc[m][n], 0, 0, 0);
        }
      }
    }
    __builtin_amdgcn_s_barrier();
  }
}

// ---------------- 128x64 GEMM core, BK=64 ----------------------------------------------------
__device__ __forceinline__ void gemm_core64(
    const u16* __restrict__ A, const u16* __restrict__ Bt,
    int lda, int ldb, int nkt, int m0, int n0,
    u16* As, u16* Bs, f32x4 (&acc)[2][4])
{
  const int tid = threadIdx.x;
  const int lane = tid & 63;
  const int w = tid >> 6;
  const int lr = lane & 15;
  const int g  = lane >> 4;

  const int sr = lane >> 3;
  const int scol = ((lane & 7) ^ sr) << 3;

  int aoff[2][2], boff[2][4];
#pragma unroll
  for (int m = 0; m < 2; ++m) {
    int ra = w*32 + m*16 + lr;
#pragma unroll
    for (int kk = 0; kk < 2; ++kk) aoff[kk][m] = ra*64 + (((kk*4+g) ^ (ra&7))<<3);
  }
#pragma unroll
  for (int n = 0; n < 4; ++n) {
    int rb = n*16 + lr;
#pragma unroll
    for (int kk = 0; kk < 2; ++kk) boff[kk][n] = rb*64 + (((kk*4+g) ^ (rb&7))<<3);
  }
  const u16* Ap = A + (size_t)m0*lda;
  const u16* Bp = Bt + (size_t)n0*ldb;

#pragma unroll
  for (int c = 0; c < 4; ++c)
    gl16(Ap + (size_t)(w*32 + c*8 + sr)*lda + scol, As + w*2048 + c*512);
#pragma unroll
  for (int c = 0; c < 2; ++c)
    gl16(Bp + (size_t)(w*16 + c*8 + sr)*ldb + scol, Bs + w*1024 + c*512);

  for (int kt = 0; kt < nkt; ++kt) {
    const int cbA = (kt & 1) * 8192;
    const int cbB = (kt & 1) * 4096;
    if (kt + 1 < nkt) {
      const int k0 = (kt + 1) << 6;
      const int nbA = ((kt + 1) & 1) * 8192;
      const int nbB = ((kt + 1) & 1) * 4096;
#pragma unroll
      for (int c = 0; c < 4; ++c)
        gl16(Ap + (size_t)(w*32 + c*8 + sr)*lda + k0 + scol, As + nbA + w*2048 + c*512);
#pragma unroll
      for (int c = 0; c < 2; ++c)
        gl16(Bp + (size_t)(w*16 + c*8 + sr)*ldb + k0 + scol, Bs + nbB + w*1024 + c*512);
      asm volatile("s_waitcnt vmcnt(6)" ::: "memory");
    } else {
      asm volatile("s_waitcnt vmcnt(0)" ::: "memory");
    }
    __builtin_amdgcn_s_barrier();

#pragma unroll
    for (int kk = 0; kk < 2; ++kk) {
      bf16x8 af[2], bfr[4];
#pragma unroll
      for (int m = 0; m < 2; ++m) af[m] = *(const bf16x8*)(As + cbA + aoff[kk][m]);
#pragma unroll
      for (int n = 0; n < 4; ++n) bfr[n] = *(const bf16x8*)(Bs + cbB + boff[kk][n]);
#pragma unroll
      for (int m = 0; m < 2; ++m) {
#pragma unroll
        for (int n = 0; n < 4; ++n) {
          acc[m][n] = __builtin_amdgcn_mfma_f32_16x16x32_bf16(af[m], bfr[n], acc[m][n], 0, 0, 0);
        }
      }
    }
    __builtin_amdgcn_s_barrier();
  }
}

// ---------------- QKV fused GEMM, 128x64 tiles (3 blocks/CU, tail-free grid) -----------------
// grid (64, 24): nt in [0,24), sel = nt>>3 (0=q,1=k,2=v), n0 = (nt&7)*64.
// q-scale folded into wqt; v written transposed into vt[bh][d][s].
__global__ __launch_bounds__(256,3) void k_qkv64(
    const u16* __restrict__ xn, const u16* __restrict__ wqt,
    const u16* __restrict__ wkt, const u16* __restrict__ wvt,
    u16* __restrict__ q, u16* __restrict__ k, u16* __restrict__ vt)
{
  __shared__ u16 As[2*128*64], Bs[2*64*64];
  int mt, nt; swz_mn(&mt, &nt);
  int m0 = mt*128;
  int sel = nt >> 3;
  int n0 = (nt & 7)*64;
  const u16* Bt = sel==0 ? wqt : (sel==1 ? wkt : wvt);
  f32x4 acc[2][4] = {};
  gemm_core64(xn, Bt, H_, H_, H_/64, m0, n0, As, Bs, acc);
  const int lane = threadIdx.x&63, w = threadIdx.x>>6;
  const int lr = lane&15, g = lane>>4;
  if (sel == 2) {
#pragma unroll
    for (int m=0;m<2;++m) {
#pragma unroll
      for (int n=0;n<4;++n) {
        int rowb = m0 + w*32 + m*16 + g*4;
        int col  = n0 + n*16 + lr;
        int b = rowb >> 11, s = rowb & 2047;
        int h = col >> 6, d = col & 63;
        u16x4 t;
#pragma unroll
        for (int r=0;r<4;++r) t[r] = (short)f2bf(acc[m][n][r]);
        *(u16x4*)(vt + ((size_t)((b*NH_ + h)*HD_ + d))*S_ + s) = t;
      }
    }
  } else {
    u16* O = sel==0 ? q : k;
#pragma unroll
    for (int m=0;m<2;++m) {
#pragma unroll
      for (int n=0;n<4;++n) {
#pragma unroll
        for (int r=0;r<4;++r) {
          int row = m0 + w*32 + m*16 + g*4 + r;
          int col = n0 + n*16 + lr;
          O[(size_t)row*H_ + col] = f2bf(acc[m][n][r]);
        }
      }
    }
  }
}

// ---------------- GEMM with epilogue, 128x128 ------------------------------------------------
// EPI 1: O(bf16) = gelu_fast(acc)
template<int EPI>
__global__ __launch_bounds__(256,2) void k_gemm(
    const u16* __restrict__ A, const u16* __restrict__ Bt, void* __restrict__ Ov,
    const void* __restrict__ aux, const float* __restrict__ maskv,
    int N, int K)
{
  __shared__ u16 As[2*128*64], Bs[2*128*64];
  int mt, nt; swz_mn(&mt, &nt);
  int m0 = mt*128, n0 = nt*128;
  f32x4 acc[4][4] = {};
  gemm_core(A, Bt, K, K, K>>6, m0, n0, As, Bs, acc);
  const int lane = threadIdx.x&63, w = threadIdx.x>>6;
  const int lr = lane&15, g = lane>>4, wr = w>>1, wc = w&1;
#pragma unroll
  for (int m=0;m<4;++m) {
#pragma unroll
    for (int n=0;n<4;++n) {
#pragma unroll
      for (int r=0;r<4;++r) {
        int row = m0 + wr*64 + m*16 + g*4 + r;
        int col = n0 + wc*64 + n*16 + lr;
        float val = acc[m][n][r];
        if (EPI == 1) {
          ((u16*)Ov)[(size_t)row*N + col] = f2bf(gelu_fast(val));
        }
      }
    }
  }
}

// ---------------- GEMM with epilogue, 128x64 -------------------------------------------------
// EPI 2: O(bf16) = (aux_f32 + acc)*maskv[row]   (Wo GEMM -> x2 in bf16)
// EPI 3: O(f32)  = acc + aux_bf16                (final: ffn + x2)
template<int EPI>
__global__ __launch_bounds__(256,3) void k_gemm64(
    const u16* __restrict__ A, const u16* __restrict__ Bt, void* __restrict__ Ov,
    const void* __restrict__ aux, const float* __restrict__ maskv,
    int N, int K)
{
  __shared__ u16 As[2*128*64], Bs[2*64*64];
  int mt, nt; swz_mn(&mt, &nt);
  int m0 = mt*128, n0 = nt*64;
  f32x4 acc[2][4] = {};
  gemm_core64(A, Bt, K, K, K>>6, m0, n0, As, Bs, acc);
  const int lane = threadIdx.x&63, w = threadIdx.x>>6;
  const int lr = lane&15, g = lane>>4;
#pragma unroll
  for (int m=0;m<2;++m) {
#pragma unroll
    for (int n=0;n<4;++n) {
#pragma unroll
      for (int r=0;r<4;++r) {
        int row = m0 + w*32 + m*16 + g*4 + r;
        int col = n0 + n*16 + lr;
        float val = acc[m][n][r];
        if (EPI == 2) {
          float mv = maskv[row];
          val = (((const float*)aux)[(size_t)row*N + col] + val)*mv;
          ((u16*)Ov)[(size_t)row*N + col] = f2bf(val);
        } else if (EPI == 3) {
          val += bf2f(((const u16*)aux)[(size_t)row*N + col]);
          ((float*)Ov)[(size_t)row*N + col] = val;
        }
      }
    }
  }
}

// ---------------- LayerNorm, bf16 input (post-attention) -------------------------------------
__global__ __launch_bounds__(256) void k_lnb(const u16* __restrict__ in,
    u16* __restrict__ out)
{
  int row = blockIdx.x*4 + (threadIdx.x>>6);
  int lane = threadIdx.x & 63;
  bf16x8 d = *(const bf16x8*)(in + (size_t)row*H_ + lane*8);
  float x[8]; float s = 0.f, s2 = 0.f;
#pragma unroll
  for (int j=0;j<8;++j){ x[j] = bf2f((u16)d[j]); s += x[j]; s2 += x[j]*x[j]; }
#pragma unroll
  for (int m=1;m<32;m<<=1){ s += __shfl_xor(s,m); s2 += __shfl_xor(s2,m); }
  s = xhalf_add(s); s2 = xhalf_add(s2);
  float mu = s*(1.0f/H_);
  float var = s2*(1.0f/H_) - mu*mu;
  float inv = rsqrtf(var + 1e-6f);
  bf16x8 o;
#pragma unroll
  for (int j=0;j<8;++j) o[j] = (short)f2bf((x[j]-mu)*inv);
  *(bf16x8*)(out + (size_t)row*H_ + lane*8) = o;
}

// ---------------- fused preprocessing: 6 weight transposes + masked LN -----------------------
// Wq is scaled by 0.125*log2e during transpose (q-scale fold).
__global__ __launch_bounds__(256) void k_pre(
    const float* __restrict__ Wq, const float* __restrict__ Wk,
    const float* __restrict__ Wv, const float* __restrict__ Wo,
    const float* __restrict__ W1, const float* __restrict__ W2,
    u16* __restrict__ wqt, u16* __restrict__ wkt, u16* __restrict__ wvt,
    u16* __restrict__ wot, u16* __restrict__ w1t, u16* __restrict__ w2t,
    const float* __restrict__ input, const float* __restrict__ mask,
    u16* __restrict__ xn)
{
  __shared__ u16 t[32][33];
  const int id = blockIdx.x;
  const int tx = threadIdx.x & 31, ty = threadIdx.x >> 5;

  if (id < 1024) {
    int z = id >> 8, tt = id & 255;
    const float* src = z==0?Wq : z==1?Wk : z==2?Wv : Wo;
    u16* dst = z==0?wqt : z==1?wkt : z==2?wvt : wot;
    float sc = (z==0) ? 0.125f*LOG2E : 1.0f;
    int c0 = (tt & 15)*32, r0 = (tt >> 4)*32;
#pragma unroll
    for (int i=0;i<32;i+=8) t[ty+i][tx] = f2bf(src[(size_t)(r0+ty+i)*512 + c0+tx]*sc);
    __syncthreads();
#pragma unroll
    for (int i=0;i<32;i+=8) dst[(size_t)(c0+ty+i)*512 + r0+tx] = t[tx][ty+i];
  } else if (id < 3072) {
    int z = (id-1024) >> 10, tt = (id-1024) & 1023;
    const float* src = z ? W2 : W1;
    u16* dst = z ? w2t : w1t;
    int R = z ? 2048 : 512;
    int C = z ? 512 : 2048;
    int a = tt & 63, bq = tt >> 6;
    int c0 = (z ? bq : a)*32;
    int r0 = (z ? a : bq)*32;
#pragma unroll
    for (int i=0;i<32;i+=8) t[ty+i][tx] = f2bf(src[(size_t)(r0+ty+i)*C + c0+tx]);
    __syncthreads();
#pragma unroll
    for (int i=0;i<32;i+=8) dst[(size_t)(c0+ty+i)*R + r0+tx] = t[tx][ty+i];
  } else {
    int row = (id-3072)*4 + (threadIdx.x>>6);
    int lane = threadIdx.x & 63;
    const f32x4* p = (const f32x4*)(input + (size_t)row*H_ + lane*8);
    f32x4 a = p[0], b = p[1];
    float mv = mask[row];
    float x[8]; float s = 0.f, s2 = 0.f;
#pragma unroll
    for (int j=0;j<4;++j){ x[j] = a[j]*mv; x[4+j] = b[j]*mv; }
#pragma unroll
    for (int j=0;j<8;++j){ s += x[j]; s2 += x[j]*x[j]; }
#pragma unroll
    for (int m=1;m<32;m<<=1){ s += __shfl_xor(s,m); s2 += __shfl_xor(s2,m); }
    s = xhalf_add(s); s2 = xhalf_add(s2);
    float mu = s*(1.0f/H_);
    float var = s2*(1.0f/H_) - mu*mu;
    float inv = rsqrtf(var + 1e-6f);
    bf16x8 o;
#pragma unroll
    for (int j=0;j<8;++j) o[j] = (short)f2bf((x[j]-mu)*inv);
    *(bf16x8*)(xn + (size_t)row*H_ + lane*8) = o;
  }
}

// ---------------- flash attention, swapped-QK^T 32x32, log2-domain softmax -------------------
__global__ __launch_bounds__(256) void k_attn(
    const u16* __restrict__ q, const u16* __restrict__ kmat,
    const u16* __restrict__ vt, const float* __restrict__ mask,
    u16* __restrict__ o)
{
  __shared__ u16 Ks[2][64*64];
  __shared__ u16 Vs[2][64*64];
  __shared__ float bias[S_];
  __shared__ float lsums[4][32];

  const int tid = threadIdx.x;
  const int lane = tid & 63;
  const int w = tid >> 6;          // 0..3
  const int l31 = lane & 31;
  const int hi = lane >> 5;
  const int bh = blockIdx.y, b = bh >> 3, h = bh & 7;
  const int q0 = blockIdx.x * 128;

  const int sr = lane >> 3;
  const int sl = (lane & 7) ^ (sr & 7);
  const u16* ks0 = kmat + (size_t)(b*S_ + w*16 + sr)*H_ + h*HD_ + sl*8;
  const u16* ks1 = ks0 + (size_t)8*H_;
  const u16* vs0 = vt + ((size_t)bh*HD_ + w*16 + sr)*S_ + sl*8;
  const u16* vs1 = vs0 + (size_t)8*S_;

  {
    u16* kd = &Ks[0][0] + w*1024;
    u16* vd = &Vs[0][0] + w*1024;
    gl16(ks0, kd); gl16(ks1, kd + 512);
    gl16(vs0, vd); gl16(vs1, vd + 512);
  }

  // bias in log2 units
  for (int j = tid; j < S_; j += 256) bias[j] = -144269.5f * (1.0f - mask[b*S_ + j]);

  bf16x8 qf[4];
  {
    const u16* qp = q + (size_t)(b*S_ + q0 + w*32 + l31)*H_ + h*HD_ + hi*8;
#pragma unroll
    for (int ds = 0; ds < 4; ++ds) qf[ds] = *(const bf16x8*)(qp + ds*16);
  }

  f32x16 po0 = {}, po1 = {};
  float mreg = -1e30f, lsum = 0.f;

  __syncthreads();   // bias + tile0 visible (full drain once)

  for (int jt = 0; jt < 32; ++jt) {
    const int buf = jt & 1;
    if (jt < 31) {
      const int j0 = (jt + 1) * 64;
      u16* kd = &Ks[buf ^ 1][0] + w*1024;
      u16* vd = &Vs[buf ^ 1][0] + w*1024;
      gl16(ks0 + (size_t)j0*H_, kd); gl16(ks1 + (size_t)j0*H_, kd + 512);
      gl16(vs0 + j0, vd);            gl16(vs1 + j0, vd + 512);
      asm volatile("s_waitcnt vmcnt(4)" ::: "memory");
    } else {
      asm volatile("s_waitcnt vmcnt(0)" ::: "memory");
    }
    __builtin_amdgcn_s_barrier();

    const u16* kt  = &Ks[buf][0];
    const u16* vtl = &Vs[buf][0];

    // ---- QK^T (S^T, log2 units), bias as MFMA C-input ----
    f32x16 s0, s1;
    const float* bp = &bias[jt*64 + hi*4];
#pragma unroll
    for (int kb = 0; kb < 2; ++kb) {
      f32x16 acc;
#pragma unroll
      for (int g2 = 0; g2 < 4; ++g2) {
        f32x4 b4 = *(const f32x4*)(bp + kb*32 + g2*8);
        acc[g2*4+0] = b4[0]; acc[g2*4+1] = b4[1];
        acc[g2*4+2] = b4[2]; acc[g2*4+3] = b4[3];
      }
      const int key = kb*32 + l31;
      const u16* kr = kt + key*64;
      __builtin_amdgcn_s_setprio(1);
#pragma unroll
      for (int ds = 0; ds < 4; ++ds) {
        bf16x8 kf = *(const bf16x8*)(kr + (((ds*2 + hi) ^ (key & 7)) << 3));
        acc = __builtin_amdgcn_mfma_f32_32x32x16_bf16(kf, qf[ds], acc, 0, 0, 0);
      }
      __builtin_amdgcn_s_setprio(0);
      if (kb == 0) s0 = acc; else s1 = acc;
    }

    // ---- online softmax; max via v_max3 fusion, exp2 single-instr ----
    float mx = fmaxf(s0[0], s1[0]);
#pragma unroll
    for (int r = 1; r < 16; ++r) mx = fmaxf(fmaxf(s0[r], s1[r]), mx);
    mx = fmaxf(mx, __shfl_xor(mx, 32));
    if (__any(mx > mreg + 8.0f)) {          // defer-max (log2 units; P <= 2^8)
      float mn = fmaxf(mreg, mx);
      float sc = __builtin_amdgcn_exp2f(mreg - mn);
      lsum *= sc;
#pragma unroll
      for (int r = 0; r < 16; ++r) { po0[r] *= sc; po1[r] *= sc; }
      mreg = mn;
    }
    float ps = 0.f;
#pragma unroll
    for (int r = 0; r < 16; ++r) { float p = __builtin_amdgcn_exp2f(s0[r]-mreg); s0[r] = p; ps += p; }
#pragma unroll
    for (int r = 0; r < 16; ++r) { float p = __builtin_amdgcn_exp2f(s1[r]-mreg); s1[r] = p; ps += p; }
    ps += __shfl_xor(ps, 32);
    lsum += ps;

    // ---- P -> A-frags (cvt_pk + permlane32_swap) + PV ----
#pragma unroll
    for (int kb = 0; kb < 2; ++kb) {
      const f32x16& sv = kb ? s1 : s0;
      u32 w01 = pk2(sv[0],  sv[1]);
      u32 w23 = pk2(sv[2],  sv[3]);
      u32 w45 = pk2(sv[4],  sv[5]);
      u32 w67 = pk2(sv[6],  sv[7]);
      asm volatile("v_permlane32_swap_b32 %0, %1" : "+v"(w01), "+v"(w45));
      asm volatile("v_permlane32_swap_b32 %0, %1" : "+v"(w23), "+v"(w67));
      u32 w89 = pk2(sv[8],  sv[9]);
      u32 wab = pk2(sv[10], sv[11]);
      u32 wcd = pk2(sv[12], sv[13]);
      u32 wef = pk2(sv[14], sv[15]);
      asm volatile("v_permlane32_swap_b32 %0, %1" : "+v"(w89), "+v"(wcd));
      asm volatile("v_permlane32_swap_b32 %0, %1" : "+v"(wab), "+v"(wef));
      union { u32 wrd[4]; bf16x8 v; } f0, f1;
      f0.wrd[0]=w01; f0.wrd[1]=w23; f0.wrd[2]=w45; f0.wrd[3]=w67;
      f1.wrd[0]=w89; f1.wrd[1]=wab; f1.wrd[2]=wcd; f1.wrd[3]=wef;
      __builtin_amdgcn_s_setprio(1);
#pragma unroll
      for (int ks = 0; ks < 2; ++ks) {
        bf16x8 pa = ks ? f1.v : f0.v;
#pragma unroll
        for (int nb = 0; nb < 2; ++nb) {
          int dd = nb*32 + l31;
          int slot = ((kb*4 + ks*2 + hi) ^ (dd & 7)) << 3;
          bf16x8 vf = *(const bf16x8*)(vtl + dd*64 + slot);
          if (nb == 0) po0 = __builtin_amdgcn_mfma_f32_32x32x16_bf16(pa, vf, po0, 0,0,0);
          else         po1 = __builtin_amdgcn_mfma_f32_32x32x16_bf16(pa, vf, po1, 0,0,0);
        }
      }
      __builtin_amdgcn_s_setprio(0);
    }
    __builtin_amdgcn_s_barrier();
  }

  // ---- epilogue ----
  if (hi == 0) lsums[w][l31] = lsum;
  f32x4 li[4];
#pragma unroll
  for (int g2i = 0; g2i < 4; ++g2i) {
    f32x4 t = *(const f32x4*)&lsums[w][g2i*8 + hi*4];
    li[g2i][0] = 1.0f/t[0]; li[g2i][1] = 1.0f/t[1];
    li[g2i][2] = 1.0f/t[2]; li[g2i][3] = 1.0f/t[3];
  }
  u16* op = o + (size_t)(b*S_ + q0 + w*32)*H_ + h*HD_;
#pragma unroll
  for (int nb = 0; nb < 2; ++nb) {
#pragma unroll
    for (int r = 0; r < 16; ++r) {
      int row = (r&3) + 8*(r>>2) + 4*hi;
      float val = (nb ? po1[r] : po0[r]) * li[r>>2][r&3];
      op[(size_t)row*H_ + nb*32 + l31] = f2bf(val);
    }
  }
}

// ---------------- launch ---------------------------------------------------------------------
extern "C" void kernel_launch(void* const* d_in, const int* in_sizes, int n_in,
                              void* d_out, int out_size, void* d_ws, size_t ws_size,
                              hipStream_t stream) {
  const float* input = (const float*)d_in[0];
  const float* mask  = (const float*)d_in[1];
  const float* Wq = (const float*)d_in[2];
  const float* Wk = (const float*)d_in[3];
  const float* Wv = (const float*)d_in[4];
  const float* Wo = (const float*)d_in[5];
  const float* W1 = (const float*)d_in[6];
  const float* W2 = (const float*)d_in[7];
  float* out = (float*)d_out;
  u16* ws = (u16*)d_ws;

  u16* wqt = ws;                 // 512x512 bf16 (pre-scaled by 0.125*log2e)
  u16* wkt = wqt + 262144;
  u16* wvt = wkt + 262144;
  u16* wot = wvt + 262144;
  u16* w1t = wot + 262144;       // 2048x512 bf16
  u16* w2t = w1t + 1048576;      // 512x2048 bf16
  u16* xn  = w2t + 1048576;      // 8192x512 bf16
  u16* q   = xn  + 4194304;
  u16* k   = q   + 4194304;
  u16* v   = k   + 4194304;      // free region
  u16* vt  = v   + 4194304;      // 32x64x2048 bf16 (written directly by k_qkv64)
  u16*   attn = xn;              // xn dead after QKV
  u16*   x2b  = q;               // q dead after attention -> 8192x512 bf16
  u16*   y    = v;               // free region
  u16*   h1   = vt;              // vt dead after attention (8192x2048 bf16)

  dim3 blk(256);
  k_pre<<<dim3(5120), blk, 0, stream>>>(Wq, Wk, Wv, Wo, W1, W2,
                                        wqt, wkt, wvt, wot, w1t, w2t,
                                        input, mask, xn);
  k_qkv64<<<dim3(64,24), blk, 0, stream>>>(xn, wqt, wkt, wvt, q, k, vt);
  k_attn<<<dim3(16,32), blk, 0, stream>>>(q, k, vt, mask, attn);
  k_gemm64<2><<<dim3(64,8), blk, 0, stream>>>(attn, wot, (void*)x2b, (const void*)input, mask, 512, 512);
  k_lnb<<<2048, blk, 0, stream>>>(x2b, y);
  k_gemm<1><<<dim3(64,16), blk, 0, stream>>>(y, w1t, (void*)h1, nullptr, nullptr, 2048, 512);
  k_gemm64<3><<<dim3(64,8), blk, 0, stream>>>(h1, w2t, (void*)out, (const void*)x2b, nullptr, 512, 2048);
}